// Round 1
// 337.243 us; speedup vs baseline: 1.0069x; 1.0069x over previous
//
#include <hip/hip_runtime.h>
#include <hip/hip_bf16.h>
#include <stdint.h>

// Problem constants (fixed by setup_inputs)
constexpr int Bn  = 8;
constexpr int Cc  = 512;
constexpr int ICc = 256;
constexpr int HWc = 48 * 48;           // 2304
constexpr float BN_EPS = 1e-5f;

typedef unsigned short u16;
typedef __attribute__((ext_vector_type(8))) short short8;   // 8 bf16 (4 VGPRs)
typedef __attribute__((ext_vector_type(4))) float f32x4;    // MFMA C/D frag

__device__ __forceinline__ u16 f2bf(float f) {
    uint32_t u = __builtin_bit_cast(uint32_t, f);
    u += 0x7fffu + ((u >> 16) & 1u);     // RNE
    return (u16)(u >> 16);
}
__device__ __forceinline__ float bf2f(u16 h) {
    uint32_t u = ((uint32_t)h) << 16;
    return __builtin_bit_cast(float, u);
}
// async global->LDS, 16B per lane; lds dst is wave-uniform base (HW adds lane*16)
__device__ __forceinline__ void load_lds16(const void* g, void* l) {
    __builtin_amdgcn_global_load_lds(
        (const __attribute__((address_space(1))) void*)(uintptr_t)g,
        (__attribute__((address_space(3))) void*)(uintptr_t)l, 16, 0, 0);
}

// ---------------------------------------------------------------------------
// Front cast: thph_w bf16 (rows 0..255=th_w, 256..511=ph_w), g_w bf16,
// bias_thph fp32 [th_b | ph_b].
// ---------------------------------------------------------------------------
__global__ __launch_bounds__(256)
void cast_front(const float* __restrict__ th_w, const float* __restrict__ ph_w,
                const float* __restrict__ g_w, const float* __restrict__ th_b,
                const float* __restrict__ ph_b, u16* __restrict__ wcat,
                float* __restrict__ bias_thph) {
    int idx = blockIdx.x * 256 + threadIdx.x;
    if (idx < 98304) {                           // ushort4 casts
        const float4* src;
        if (idx < 32768)       src = (const float4*)th_w + idx;
        else if (idx < 65536)  src = (const float4*)ph_w + (idx - 32768);
        else                   src = (const float4*)g_w  + (idx - 65536);
        float4 v = *src;
        ushort4 o;
        o.x = f2bf(v.x); o.y = f2bf(v.y); o.z = f2bf(v.z); o.w = f2bf(v.w);
        ((ushort4*)wcat)[idx] = o;
    } else if (idx < 98816) {                    // 512 bias floats
        int i = idx - 98304;
        bias_thph[i] = (i < 256) ? th_b[i] : ph_b[i - 256];
    }
}

__global__ __launch_bounds__(256)
void cast_w(const float* __restrict__ a, u16* __restrict__ out) {
    int idx = blockIdx.x * 256 + threadIdx.x;    // 0..32767
    float4 v = ((const float4*)a)[idx];
    ushort4 o;
    o.x = f2bf(v.x); o.y = f2bf(v.y); o.z = f2bf(v.z); o.w = f2bf(v.w);
    ((ushort4*)out)[idx] = o;
}

// ---------------------------------------------------------------------------
// x (B,C,HW) fp32 -> xt (B,HW,C) bf16, 64c x 32p LDS-tiled, ushort2 stores
// ---------------------------------------------------------------------------
__global__ __launch_bounds__(256)
void transpose_cast_x(const float* __restrict__ x, u16* __restrict__ xt) {
    __shared__ float t[64][33];
    const int b = blockIdx.z;
    const int p0 = blockIdx.x * 32;     // HW dir
    const int c0 = blockIdx.y * 64;     // C dir
    const int tx = threadIdx.x & 31, ty = threadIdx.x >> 5;   // ty 0..7
    const float* xb = x + (size_t)b * Cc * HWc;
#pragma unroll
    for (int r = 0; r < 8; ++r)
        t[r * 8 + ty][tx] = xb[(size_t)(c0 + r * 8 + ty) * HWc + p0 + tx];
    __syncthreads();
    u16* xtb = xt + (size_t)b * HWc * Cc;
    const int cc = (threadIdx.x & 31) * 2, pp = threadIdx.x >> 5;
#pragma unroll
    for (int r = 0; r < 4; ++r) {
        int p = r * 8 + pp;
        ushort2 v;
        v.x = f2bf(t[cc][p]);
        v.y = f2bf(t[cc + 1][p]);
        *(ushort2*)&xtb[(size_t)(p0 + p) * Cc + c0 + cc] = v;
    }
}

// ---------------------------------------------------------------------------
// bf16 MFMA GEMM: C[m][n] = sum_k A[m][k] * B[n][k] (+ bias)
//   A: (M,K) bf16, B: (N,K) bf16, both K-contiguous.
//   TM=128: 128x128 tile, wave layout 2x2 (64x64 each).
//   TM=64 :  64x128 tile, wave layout 2x2 (32x64 each).
// 2-phase software pipeline (T3-minimum recipe): double-buffered LDS, the
// global_load_lds for K-step t+1 is issued BEFORE the ds_read+MFMA of step t,
// single barrier per step. The pre-barrier vmcnt(0) drain then overlaps the
// load latency with compute instead of serializing (latency-bound before:
// MfmaUtil 15%, Occ 17%, 33% HBM).
// STORE==0: bf16 C; STORE==1: fp32 C. STATS: fused per-channel(m) sum/sumsq
// via 16-lane shuffle reduce + atomicAdd (BatchNorm over n and batch).
// bias_mode: 0 none, 1 per-n, 2 per-m.
// ---------------------------------------------------------------------------
template <int TM, int STORE, bool STATS>
__global__ __launch_bounds__(256, 2)
void mfma_gemm(const u16* __restrict__ A, const u16* __restrict__ B,
               void* __restrict__ Cout, const float* __restrict__ bias,
               int bias_mode, int K, int ldA, int ldB, int ldC,
               size_t sA, size_t sB, size_t sC,
               float* __restrict__ s0g, float* __restrict__ s1g) {
    constexpr int MI = TM / 32;                  // 4 (TM=128) or 2 (TM=64)
    __shared__ __align__(16) u16 As[2][TM * 32];
    __shared__ __align__(16) u16 Bs[2][128 * 32];
    const int bz = blockIdx.z;
    const int m0 = blockIdx.y * TM, n0 = blockIdx.x * 128;
    const u16* Ab = A + (size_t)bz * sA + (size_t)m0 * ldA;
    const u16* Bb = B + (size_t)bz * sB + (size_t)n0 * ldB;
    const int tid = threadIdx.x, lane = tid & 63, w = tid >> 6;
    const int wm = (w & 1) * (TM / 2);
    const int wn = (w >> 1) * 64;
    const int quad = lane >> 4, m16 = lane & 15;

    f32x4 acc[MI][4];
#pragma unroll
    for (int i = 0; i < MI; ++i)
#pragma unroll
        for (int j = 0; j < 4; ++j) acc[i][j] = (f32x4){0.f, 0.f, 0.f, 0.f};

    // staging: linear slot L -> row = L>>2, k-chunk = (L&3)*8
    const int L0 = 2 * w * 64 + lane, L1 = L0 + 64;
    const int br0 = L0 >> 2, bc0 = (L0 & 3) * 8;
    const int br1 = L1 >> 2, bc1 = (L1 & 3) * 8;
    const int ar0 = (TM == 128) ? br0 : (tid >> 2);
    const int ac0 = (TM == 128) ? bc0 : (tid & 3) * 8;

    auto stage = [&](int buf, int k0) {
        if (TM == 128) {
            load_lds16(Ab + (size_t)ar0 * ldA + k0 + ac0, &As[buf][2 * w * 512]);
            load_lds16(Ab + (size_t)br1 * ldA + k0 + bc1, &As[buf][(2 * w + 1) * 512]);
        } else {
            load_lds16(Ab + (size_t)ar0 * ldA + k0 + ac0, &As[buf][w * 512]);
        }
        load_lds16(Bb + (size_t)br0 * ldB + k0 + bc0, &Bs[buf][2 * w * 512]);
        load_lds16(Bb + (size_t)br1 * ldB + k0 + bc1, &Bs[buf][(2 * w + 1) * 512]);
    };

    // prologue: fill buffer 0, wait (vmcnt drain inside __syncthreads)
    stage(0, 0);
    __syncthreads();

    int cur = 0;
    for (int k0 = 0; k0 < K; k0 += 32) {
        // issue next K-step's loads into the other buffer (in flight across
        // the compute below; drained by the barrier at loop bottom)
        if (k0 + 32 < K) stage(cur ^ 1, k0 + 32);

        short8 af[MI], bfv[4];
#pragma unroll
        for (int i = 0; i < MI; ++i)
            af[i] = *(const short8*)&As[cur][(wm + i * 16 + m16) * 32 + quad * 8];
#pragma unroll
        for (int j = 0; j < 4; ++j)
            bfv[j] = *(const short8*)&Bs[cur][(wn + j * 16 + m16) * 32 + quad * 8];
#pragma unroll
        for (int i = 0; i < MI; ++i)
#pragma unroll
            for (int j = 0; j < 4; ++j)
                acc[i][j] = __builtin_amdgcn_mfma_f32_16x16x32_bf16(
                    af[i], bfv[j], acc[i][j], 0, 0, 0);

        // one barrier per K-step: ensures (a) this buffer's reads done before
        // it gets re-staged next iteration, (b) next buffer's loads landed.
        __syncthreads();
        cur ^= 1;
    }

    // bias into acc (C/D layout m89: col n = lane&15, row m = quad*4 + reg)
    if (bias_mode) {
#pragma unroll
        for (int i = 0; i < MI; ++i)
#pragma unroll
            for (int j = 0; j < 4; ++j)
#pragma unroll
                for (int r = 0; r < 4; ++r)
                    acc[i][j][r] += (bias_mode == 2)
                        ? bias[m0 + wm + i * 16 + quad * 4 + r]
                        : bias[n0 + wn + j * 16 + m16];
    }

    if (STORE == 0) {
        u16* C = (u16*)Cout + (size_t)bz * sC;
#pragma unroll
        for (int i = 0; i < MI; ++i) {
            int m = m0 + wm + i * 16 + quad * 4;
#pragma unroll
            for (int j = 0; j < 4; ++j) {
                int n = n0 + wn + j * 16 + m16;
#pragma unroll
                for (int r = 0; r < 4; ++r)
                    C[(size_t)(m + r) * ldC + n] = f2bf(acc[i][j][r]);
            }
        }
    } else {
        float* C = (float*)Cout + (size_t)bz * sC;
#pragma unroll
        for (int i = 0; i < MI; ++i) {
            int m = m0 + wm + i * 16 + quad * 4;
#pragma unroll
            for (int j = 0; j < 4; ++j) {
                int n = n0 + wn + j * 16 + m16;
#pragma unroll
                for (int r = 0; r < 4; ++r)
                    C[(size_t)(m + r) * ldC + n] = acc[i][j][r];
            }
        }
    }

    if (STATS) {
        // per-row partial sums over this wave's 64 n-cols, then atomic
#pragma unroll
        for (int i = 0; i < MI; ++i) {
#pragma unroll
            for (int r = 0; r < 4; ++r) {
                float v0 = 0.f, v1 = 0.f;
#pragma unroll
                for (int j = 0; j < 4; ++j) {
                    float v = acc[i][j][r];
                    v0 += v;
                    v1 = fmaf(v, v, v1);
                }
#pragma unroll
                for (int off = 8; off; off >>= 1) {
                    v0 += __shfl_down(v0, off, 16);
                    v1 += __shfl_down(v1, off, 16);
                }
                if (m16 == 0) {
                    int m = m0 + wm + i * 16 + quad * 4 + r;
                    atomicAdd(&s0g[m], v0);
                    atomicAdd(&s1g[m], v1);
                }
            }
        }
    }
}

// ---------------------------------------------------------------------------
// In-place row softmax on bf16 S (rows of 2304). 192 threads, 12 elems each.
// ---------------------------------------------------------------------------
__global__ __launch_bounds__(192)
void softmax_rows(u16* __restrict__ S) {
    const int b = blockIdx.x & 7;
    const int q = blockIdx.x >> 3;
    u16* row = S + ((size_t)b * HWc + q) * (size_t)HWc;
    const int tid = threadIdx.x;

    float v[12];
#pragma unroll
    for (int c = 0; c < 3; ++c) {
        uint2 raw = *(const uint2*)&row[(c * 192 + tid) * 4];
        v[c * 4 + 0] = bf2f((u16)(raw.x & 0xffff));
        v[c * 4 + 1] = bf2f((u16)(raw.x >> 16));
        v[c * 4 + 2] = bf2f((u16)(raw.y & 0xffff));
        v[c * 4 + 3] = bf2f((u16)(raw.y >> 16));
    }
    float m = v[0];
#pragma unroll
    for (int i = 1; i < 12; ++i) m = fmaxf(m, v[i]);
#pragma unroll
    for (int off = 32; off; off >>= 1) m = fmaxf(m, __shfl_down(m, off, 64));
    __shared__ float redm[3], reds[3];
    if ((tid & 63) == 0) redm[tid >> 6] = m;
    __syncthreads();
    m = fmaxf(fmaxf(redm[0], redm[1]), redm[2]);

    float s = 0.f;
#pragma unroll
    for (int i = 0; i < 12; ++i) { v[i] = __expf(v[i] - m); s += v[i]; }
#pragma unroll
    for (int off = 32; off; off >>= 1) s += __shfl_down(s, off, 64);
    if ((tid & 63) == 0) reds[tid >> 6] = s;
    __syncthreads();
    const float rinv = 1.0f / (reds[0] + reds[1] + reds[2]);

#pragma unroll
    for (int c = 0; c < 3; ++c) {
        uint2 o;
        o.x = (uint32_t)f2bf(v[c * 4 + 0] * rinv) |
              ((uint32_t)f2bf(v[c * 4 + 1] * rinv) << 16);
        o.y = (uint32_t)f2bf(v[c * 4 + 2] * rinv) |
              ((uint32_t)f2bf(v[c * 4 + 3] * rinv) << 16);
        *(uint2*)&row[(c * 192 + tid) * 4] = o;
    }
}

// ---------------------------------------------------------------------------
// Normalize (from raw sums) + affine + residual, float4 vectorized
// ---------------------------------------------------------------------------
__global__ __launch_bounds__(256)
void bn_apply(const float* __restrict__ wy, const float* __restrict__ x,
              const float* __restrict__ s0, const float* __restrict__ s1,
              const float* __restrict__ gamma, const float* __restrict__ beta,
              float* __restrict__ out) {
    const size_t i4 = (size_t)blockIdx.x * 256 + threadIdx.x;
    const size_t base = i4 * 4;
    const int o = (int)((base / HWc) % Cc);
    const float N = (float)(Bn * HWc);
    const float mean = s0[o] / N;
    const float var  = s1[o] / N - mean * mean;
    const float rstd = rsqrtf(var + BN_EPS);
    const float ga = gamma[o];
    const float be = beta[o];
    const float4 w4 = ((const float4*)wy)[i4];
    const float4 x4 = ((const float4*)x)[i4];
    float4 r;
    r.x = (w4.x - mean) * rstd * ga + be + x4.x;
    r.y = (w4.y - mean) * rstd * ga + be + x4.y;
    r.z = (w4.z - mean) * rstd * ga + be + x4.z;
    r.w = (w4.w - mean) * rstd * ga + be + x4.w;
    ((float4*)out)[i4] = r;
}

// ---------------------------------------------------------------------------
extern "C" void kernel_launch(void* const* d_in, const int* in_sizes, int n_in,
                              void* d_out, int out_size, void* d_ws, size_t ws_size,
                              hipStream_t stream) {
    const float* x     = (const float*)d_in[0];
    const float* g_w   = (const float*)d_in[1];
    const float* g_b   = (const float*)d_in[2];
    const float* th_w  = (const float*)d_in[3];
    const float* th_b  = (const float*)d_in[4];
    const float* ph_w  = (const float*)d_in[5];
    const float* ph_b  = (const float*)d_in[6];
    const float* w_w   = (const float*)d_in[7];
    const float* w_b   = (const float*)d_in[8];
    const float* gamma = (const float*)d_in[9];
    const float* beta  = (const float*)d_in[10];

    // Workspace aliasing (113.25 MB total, same bound as previous rounds):
    //  [0, 18.87M)      thph bf16 (B,HW,512)  -> later y bf16 (B,HW,IC) at [0,9.44M)
    //                   and post-S: wbf2 + stats at [9.44M, ...)
    //  [18.87M, 28.31M) g bf16 (B,IC,HW)
    //  [28.31M, 113.25M) Sreg: pre-S hosts xt bf16 (B,HW,C) + wcat + bias_thph;
    //                   S bf16 (B,HW,HW); post-PV wy fp32 (B,C,HW)
    char* base = (char*)d_ws;
    const size_t SZT = (size_t)Bn * HWc * ICc * 2;        // 9,437,184
    u16* thph = (u16*)base;                               // 18.87 MB
    u16* g    = (u16*)(base + 2 * SZT);                   // 9.44 MB
    char* Sreg = base + 3 * SZT;
    u16* S    = (u16*)Sreg;                               // 84.93 MB
    u16* xt   = (u16*)Sreg;                               // 18.87 MB (pre-S)
    u16* wcat = (u16*)(Sreg + (size_t)Bn * HWc * Cc * 2); // 786 KB (pre-S)
    float* bias_thph = (float*)(Sreg + (size_t)Bn * HWc * Cc * 2 + 786432);
    u16* y    = (u16*)base;                               // 9.44 MB (post-S)
    u16* wbf2 = (u16*)(base + SZT);                       // 262 KB (post-S)
    float* stats = (float*)(base + SZT + 262144);         // 4 KB (post-S)
    float* wy = (float*)Sreg;                             // 37.75 MB (post-PV)

    dim3 blk(256);
    const u16* thphw = wcat;                   // (512,512)
    const u16* gwb   = wcat + 262144;          // (256,512)

    cast_front<<<dim3(386), blk, 0, stream>>>(th_w, ph_w, g_w, th_b, ph_b,
                                              wcat, bias_thph);
    transpose_cast_x<<<dim3(HWc / 32, Cc / 64, Bn), blk, 0, stream>>>(x, xt);

    // thph[q][o] = sum_c xt[q][c]*thph_w[o][c] + bias  (M=2304,N=512,K=512)
    mfma_gemm<128, 0, false><<<dim3(4, 18, Bn), blk, 0, stream>>>(
        xt, thphw, thph, bias_thph, 1, Cc, Cc, Cc, 512,
        (size_t)HWc * Cc, 0, (size_t)HWc * 512, nullptr, nullptr);

    // g[ic][p] = sum_c g_w[ic][c]*xt[p][c] + g_b[ic]   (M=256,N=2304,K=512)
    mfma_gemm<64, 0, false><<<dim3(18, 4, Bn), blk, 0, stream>>>(
        gwb, xt, g, g_b, 2, Cc, Cc, Cc, HWc,
        0, (size_t)HWc * Cc, (size_t)ICc * HWc, nullptr, nullptr);

    // S = tht . pht^T   (M=N=2304, K=256); tht = thph cols 0..255, pht = +256
    mfma_gemm<128, 0, false><<<dim3(18, 18, Bn), blk, 0, stream>>>(
        thph, thph + 256, S, nullptr, 0, ICc, 512, 512, HWc,
        (size_t)HWc * 512, (size_t)HWc * 512, (size_t)HWc * HWc,
        nullptr, nullptr);

    // w_w -> bf16 and zero stats (into regions dead after S-gemm)
    cast_w<<<dim3(128), blk, 0, stream>>>(w_w, wbf2);
    hipMemsetAsync(stats, 0, 2 * Cc * sizeof(float), stream);

    // softmax rows, in place
    softmax_rows<<<dim3(Bn * HWc), dim3(192), 0, stream>>>(S);

    // y[q][ic] = sum_k P[q][k]*g[ic][k]  (M=2304,N=256,K=2304), TM=64: 576 blk
    mfma_gemm<64, 0, false><<<dim3(2, 36, Bn), blk, 0, stream>>>(
        S, g, y, nullptr, 0, HWc, HWc, HWc, ICc,
        (size_t)HWc * HWc, (size_t)ICc * HWc, (size_t)HWc * ICc,
        nullptr, nullptr);

    // wy[o][p] = sum_ic w_w[o][ic]*y[p][ic] + w_b[o]  (M=512,N=2304,K=256)
    // fp32 out + fused BN sum/sumsq
    mfma_gemm<128, 1, true><<<dim3(18, 4, Bn), blk, 0, stream>>>(
        wbf2, y, wy, w_b, 2, ICc, ICc, ICc, HWc,
        0, (size_t)HWc * ICc, (size_t)Cc * HWc, stats, stats + Cc);

    // BatchNorm apply (stats from raw sums) + affine + residual
    bn_apply<<<dim3((Bn * Cc * HWc) / 4 / 256), blk, 0, stream>>>(
        wy, x, stats, stats + Cc, gamma, beta, (float*)d_out);
}

// Round 2
// 321.144 us; speedup vs baseline: 1.0574x; 1.0501x over previous
//
#include <hip/hip_runtime.h>
#include <hip/hip_bf16.h>
#include <stdint.h>

// Problem constants (fixed by setup_inputs)
constexpr int Bn  = 8;
constexpr int Cc  = 512;
constexpr int ICc = 256;
constexpr int HWc = 48 * 48;           // 2304
constexpr float BN_EPS = 1e-5f;

typedef unsigned short u16;
typedef __attribute__((ext_vector_type(8))) short short8;   // 8 bf16 (4 VGPRs)
typedef __attribute__((ext_vector_type(4))) float f32x4;    // MFMA C/D frag

__device__ __forceinline__ u16 f2bf(float f) {
    uint32_t u = __builtin_bit_cast(uint32_t, f);
    u += 0x7fffu + ((u >> 16) & 1u);     // RNE
    return (u16)(u >> 16);
}
__device__ __forceinline__ float bf2f(u16 h) {
    uint32_t u = ((uint32_t)h) << 16;
    return __builtin_bit_cast(float, u);
}
// async global->LDS, 16B per lane; lds dst is wave-uniform base (HW adds lane*16)
__device__ __forceinline__ void load_lds16(const void* g, void* l) {
    __builtin_amdgcn_global_load_lds(
        (const __attribute__((address_space(1))) void*)(uintptr_t)g,
        (__attribute__((address_space(3))) void*)(uintptr_t)l, 16, 0, 0);
}
template <int N> __device__ __forceinline__ void wait_vmcnt() {
    if constexpr (N == 0)      asm volatile("s_waitcnt vmcnt(0)" ::: "memory");
    else if constexpr (N == 3) asm volatile("s_waitcnt vmcnt(3)" ::: "memory");
    else if constexpr (N == 4) asm volatile("s_waitcnt vmcnt(4)" ::: "memory");
    else if constexpr (N == 6) asm volatile("s_waitcnt vmcnt(6)" ::: "memory");
    else if constexpr (N == 8) asm volatile("s_waitcnt vmcnt(8)" ::: "memory");
}
__device__ __forceinline__ void wait_lgkm0() {
    asm volatile("s_waitcnt lgkmcnt(0)" ::: "memory");
}
__device__ __forceinline__ void barrier_fenced() {
    __builtin_amdgcn_s_barrier();
    asm volatile("" ::: "memory");      // keep LDS reads below the barrier
}

// ---------------------------------------------------------------------------
// Front cast: thph_w bf16 (rows 0..255=th_w, 256..511=ph_w), g_w bf16,
// bias_thph fp32 [th_b | ph_b].
// ---------------------------------------------------------------------------
__global__ __launch_bounds__(256)
void cast_front(const float* __restrict__ th_w, const float* __restrict__ ph_w,
                const float* __restrict__ g_w, const float* __restrict__ th_b,
                const float* __restrict__ ph_b, u16* __restrict__ wcat,
                float* __restrict__ bias_thph) {
    int idx = blockIdx.x * 256 + threadIdx.x;
    if (idx < 98304) {                           // ushort4 casts
        const float4* src;
        if (idx < 32768)       src = (const float4*)th_w + idx;
        else if (idx < 65536)  src = (const float4*)ph_w + (idx - 32768);
        else                   src = (const float4*)g_w  + (idx - 65536);
        float4 v = *src;
        ushort4 o;
        o.x = f2bf(v.x); o.y = f2bf(v.y); o.z = f2bf(v.z); o.w = f2bf(v.w);
        ((ushort4*)wcat)[idx] = o;
    } else if (idx < 98816) {                    // 512 bias floats
        int i = idx - 98304;
        bias_thph[i] = (i < 256) ? th_b[i] : ph_b[i - 256];
    }
}

__global__ __launch_bounds__(256)
void cast_w(const float* __restrict__ a, u16* __restrict__ out) {
    int idx = blockIdx.x * 256 + threadIdx.x;    // 0..32767
    float4 v = ((const float4*)a)[idx];
    ushort4 o;
    o.x = f2bf(v.x); o.y = f2bf(v.y); o.z = f2bf(v.z); o.w = f2bf(v.w);
    ((ushort4*)out)[idx] = o;
}

// ---------------------------------------------------------------------------
// x (B,C,HW) fp32 -> xt (B,HW,C) bf16, 64c x 32p LDS-tiled, ushort2 stores
// ---------------------------------------------------------------------------
__global__ __launch_bounds__(256)
void transpose_cast_x(const float* __restrict__ x, u16* __restrict__ xt) {
    __shared__ float t[64][33];
    const int b = blockIdx.z;
    const int p0 = blockIdx.x * 32;     // HW dir
    const int c0 = blockIdx.y * 64;     // C dir
    const int tx = threadIdx.x & 31, ty = threadIdx.x >> 5;   // ty 0..7
    const float* xb = x + (size_t)b * Cc * HWc;
#pragma unroll
    for (int r = 0; r < 8; ++r)
        t[r * 8 + ty][tx] = xb[(size_t)(c0 + r * 8 + ty) * HWc + p0 + tx];
    __syncthreads();
    u16* xtb = xt + (size_t)b * HWc * Cc;
    const int cc = (threadIdx.x & 31) * 2, pp = threadIdx.x >> 5;
#pragma unroll
    for (int r = 0; r < 4; ++r) {
        int p = r * 8 + pp;
        ushort2 v;
        v.x = f2bf(t[cc][p]);
        v.y = f2bf(t[cc + 1][p]);
        *(ushort2*)&xtb[(size_t)(p0 + p) * Cc + c0 + cc] = v;
    }
}

// ---------------------------------------------------------------------------
// bf16 MFMA GEMM: C[m][n] = sum_k A[m][k] * B[n][k] (+ bias)
//   A: (M,K) bf16, B: (N,K) bf16, both K-contiguous.
//   TM=128: 128x128 tile, wave layout 2x2 (64x64 each).
//   TM=64 :  64x128 tile, wave layout 2x2 (32x64 each).
//
// 3-buffer pipeline, prefetch depth 2, counted vmcnt (T3/T4): stage(t+2) is
// issued each step; `s_waitcnt vmcnt(2*LPS)` waits only for stage(t) — loads
// get TWO compute phases to land instead of being drained at every barrier
// (previous 2-buffer version still hit vmcnt(0) inside __syncthreads; MfmaUtil
// stuck at 15%). Raw s_barrier + asm waits per m139/m201 pattern; lgkmcnt(0)
// before the tail barrier so no wave leaves the compute phase with LDS reads
// outstanding (buffer about to be re-staged).
//
// LDS XOR swizzle (T2, rule 21: linear dest + inverse-swizzled SOURCE +
// swizzled READ): 16B chunk q of row r lives at slot q ^ ((r>>1)&3). Spreads
// the 16 m16-lanes of a quarter-wave over all 8 (bank-group x parity)
// positions -> 2-way (free) instead of 8-way. Read-side index is the per-lane
// constant quad ^ ((m16>>1)&3).
//
// STORE==0: bf16 C; STORE==1: fp32 C. STATS: fused per-channel(m) sum/sumsq
// via 16-lane shuffle reduce + atomicAdd. bias_mode: 0 none, 1 per-n, 2 per-m.
// ---------------------------------------------------------------------------
template <int TM, int STORE, bool STATS>
__global__ __launch_bounds__(256, 2)
void mfma_gemm(const u16* __restrict__ A, const u16* __restrict__ B,
               void* __restrict__ Cout, const float* __restrict__ bias,
               int bias_mode, int K, int ldA, int ldB, int ldC,
               size_t sA, size_t sB, size_t sC,
               float* __restrict__ s0g, float* __restrict__ s1g) {
    constexpr int MI  = TM / 32;                 // 4 (TM=128) or 2 (TM=64)
    constexpr int LPS = (TM == 128) ? 4 : 3;     // global_load_lds per wave/stage
    __shared__ __align__(16) u16 As[3][TM * 32];
    __shared__ __align__(16) u16 Bs[3][128 * 32];
    const int bz = blockIdx.z;
    const int m0 = blockIdx.y * TM, n0 = blockIdx.x * 128;
    const u16* Ab = A + (size_t)bz * sA + (size_t)m0 * ldA;
    const u16* Bb = B + (size_t)bz * sB + (size_t)n0 * ldB;
    const int tid = threadIdx.x, lane = tid & 63, w = tid >> 6;
    const int wm = (w & 1) * (TM / 2);
    const int wn = (w >> 1) * 64;
    const int quad = lane >> 4, m16 = lane & 15;

    f32x4 acc[MI][4];
#pragma unroll
    for (int i = 0; i < MI; ++i)
#pragma unroll
        for (int j = 0; j < 4; ++j) acc[i][j] = (f32x4){0.f, 0.f, 0.f, 0.f};

    // staging: linear slot L -> row = L>>2; SOURCE chunk = (L&3)^((L>>3)&3)
    // (inverse of the read swizzle; both are the same involution)
    const int L0 = 2 * w * 64 + lane, L1 = L0 + 64;
    const int br0 = L0 >> 2, bc0 = ((L0 & 3) ^ ((L0 >> 3) & 3)) * 8;
    const int br1 = L1 >> 2, bc1 = ((L1 & 3) ^ ((L1 >> 3) & 3)) * 8;
    const int ar0 = (TM == 128) ? br0 : (tid >> 2);
    const int ac0 = (TM == 128) ? bc0 : (((tid & 3) ^ ((tid >> 3) & 3)) * 8);

    auto stage = [&](int buf, int k0) {
        if (TM == 128) {
            load_lds16(Ab + (size_t)ar0 * ldA + k0 + ac0, &As[buf][2 * w * 512]);
            load_lds16(Ab + (size_t)br1 * ldA + k0 + bc1, &As[buf][(2 * w + 1) * 512]);
        } else {
            load_lds16(Ab + (size_t)ar0 * ldA + k0 + ac0, &As[buf][w * 512]);
        }
        load_lds16(Bb + (size_t)br0 * ldB + k0 + bc0, &Bs[buf][2 * w * 512]);
        load_lds16(Bb + (size_t)br1 * ldB + k0 + bc1, &Bs[buf][(2 * w + 1) * 512]);
    };

    // swizzled read: chunk quad of row r is at slot quad ^ ((r>>1)&3);
    // (r>>1)&3 == (m16>>1)&3 for every row this lane touches.
    const int sq = (quad ^ ((m16 >> 1) & 3)) * 8;

    auto compute = [&](int buf) {
        short8 af[MI], bfv[4];
#pragma unroll
        for (int i = 0; i < MI; ++i)
            af[i] = *(const short8*)&As[buf][(wm + i * 16 + m16) * 32 + sq];
#pragma unroll
        for (int j = 0; j < 4; ++j)
            bfv[j] = *(const short8*)&Bs[buf][(wn + j * 16 + m16) * 32 + sq];
#pragma unroll
        for (int i = 0; i < MI; ++i)
#pragma unroll
            for (int j = 0; j < 4; ++j)
                acc[i][j] = __builtin_amdgcn_mfma_f32_16x16x32_bf16(
                    af[i], bfv[j], acc[i][j], 0, 0, 0);
    };

    const int nt = K / 32;                       // >= 8 for all our shapes
    // prologue: fill buffers 0 and 1 (2*LPS loads in flight)
    stage(0, 0);
    stage(1, 32);

    int cur = 0;
    for (int t = 0; t < nt - 2; ++t) {
        int nxt = cur + 2; if (nxt >= 3) nxt -= 3;
        stage(nxt, (t + 2) * 32);                // buf consumed at t-1; safe
        wait_vmcnt<2 * LPS>();                   // stage(t) landed (t+1,t+2 fly)
        barrier_fenced();                        // ...for ALL waves
        compute(cur);
        wait_lgkm0();                            // our LDS reads done
        barrier_fenced();                        // all waves done with buf[cur]
        ++cur; if (cur == 3) cur = 0;
    }
    // t = nt-2: stages nt-2, nt-1 outstanding
    wait_vmcnt<LPS>();
    barrier_fenced();
    compute(cur);
    wait_lgkm0();
    barrier_fenced();
    ++cur; if (cur == 3) cur = 0;
    // t = nt-1: last stage outstanding
    wait_vmcnt<0>();
    barrier_fenced();
    compute(cur);

    // bias into acc (C/D layout m89: col n = lane&15, row m = quad*4 + reg)
    if (bias_mode) {
#pragma unroll
        for (int i = 0; i < MI; ++i)
#pragma unroll
            for (int j = 0; j < 4; ++j)
#pragma unroll
                for (int r = 0; r < 4; ++r)
                    acc[i][j][r] += (bias_mode == 2)
                        ? bias[m0 + wm + i * 16 + quad * 4 + r]
                        : bias[n0 + wn + j * 16 + m16];
    }

    if (STORE == 0) {
        u16* C = (u16*)Cout + (size_t)bz * sC;
#pragma unroll
        for (int i = 0; i < MI; ++i) {
            int m = m0 + wm + i * 16 + quad * 4;
#pragma unroll
            for (int j = 0; j < 4; ++j) {
                int n = n0 + wn + j * 16 + m16;
#pragma unroll
                for (int r = 0; r < 4; ++r)
                    C[(size_t)(m + r) * ldC + n] = f2bf(acc[i][j][r]);
            }
        }
    } else {
        float* C = (float*)Cout + (size_t)bz * sC;
#pragma unroll
        for (int i = 0; i < MI; ++i) {
            int m = m0 + wm + i * 16 + quad * 4;
#pragma unroll
            for (int j = 0; j < 4; ++j) {
                int n = n0 + wn + j * 16 + m16;
#pragma unroll
                for (int r = 0; r < 4; ++r)
                    C[(size_t)(m + r) * ldC + n] = acc[i][j][r];
            }
        }
    }

    if (STATS) {
        // per-row partial sums over this wave's 64 n-cols, then atomic
#pragma unroll
        for (int i = 0; i < MI; ++i) {
#pragma unroll
            for (int r = 0; r < 4; ++r) {
                float v0 = 0.f, v1 = 0.f;
#pragma unroll
                for (int j = 0; j < 4; ++j) {
                    float v = acc[i][j][r];
                    v0 += v;
                    v1 = fmaf(v, v, v1);
                }
#pragma unroll
                for (int off = 8; off; off >>= 1) {
                    v0 += __shfl_down(v0, off, 16);
                    v1 += __shfl_down(v1, off, 16);
                }
                if (m16 == 0) {
                    int m = m0 + wm + i * 16 + quad * 4 + r;
                    atomicAdd(&s0g[m], v0);
                    atomicAdd(&s1g[m], v1);
                }
            }
        }
    }
}

// ---------------------------------------------------------------------------
// In-place row softmax on bf16 S (rows of 2304). 192 threads, 12 elems each.
// ---------------------------------------------------------------------------
__global__ __launch_bounds__(192)
void softmax_rows(u16* __restrict__ S) {
    const int b = blockIdx.x & 7;
    const int q = blockIdx.x >> 3;
    u16* row = S + ((size_t)b * HWc + q) * (size_t)HWc;
    const int tid = threadIdx.x;

    float v[12];
#pragma unroll
    for (int c = 0; c < 3; ++c) {
        uint2 raw = *(const uint2*)&row[(c * 192 + tid) * 4];
        v[c * 4 + 0] = bf2f((u16)(raw.x & 0xffff));
        v[c * 4 + 1] = bf2f((u16)(raw.x >> 16));
        v[c * 4 + 2] = bf2f((u16)(raw.y & 0xffff));
        v[c * 4 + 3] = bf2f((u16)(raw.y >> 16));
    }
    float m = v[0];
#pragma unroll
    for (int i = 1; i < 12; ++i) m = fmaxf(m, v[i]);
#pragma unroll
    for (int off = 32; off; off >>= 1) m = fmaxf(m, __shfl_down(m, off, 64));
    __shared__ float redm[3], reds[3];
    if ((tid & 63) == 0) redm[tid >> 6] = m;
    __syncthreads();
    m = fmaxf(fmaxf(redm[0], redm[1]), redm[2]);

    float s = 0.f;
#pragma unroll
    for (int i = 0; i < 12; ++i) { v[i] = __expf(v[i] - m); s += v[i]; }
#pragma unroll
    for (int off = 32; off; off >>= 1) s += __shfl_down(s, off, 64);
    if ((tid & 63) == 0) reds[tid >> 6] = s;
    __syncthreads();
    const float rinv = 1.0f / (reds[0] + reds[1] + reds[2]);

#pragma unroll
    for (int c = 0; c < 3; ++c) {
        uint2 o;
        o.x = (uint32_t)f2bf(v[c * 4 + 0] * rinv) |
              ((uint32_t)f2bf(v[c * 4 + 1] * rinv) << 16);
        o.y = (uint32_t)f2bf(v[c * 4 + 2] * rinv) |
              ((uint32_t)f2bf(v[c * 4 + 3] * rinv) << 16);
        *(uint2*)&row[(c * 192 + tid) * 4] = o;
    }
}

// ---------------------------------------------------------------------------
// Normalize (from raw sums) + affine + residual, float4 vectorized
// ---------------------------------------------------------------------------
__global__ __launch_bounds__(256)
void bn_apply(const float* __restrict__ wy, const float* __restrict__ x,
              const float* __restrict__ s0, const float* __restrict__ s1,
              const float* __restrict__ gamma, const float* __restrict__ beta,
              float* __restrict__ out) {
    const size_t i4 = (size_t)blockIdx.x * 256 + threadIdx.x;
    const size_t base = i4 * 4;
    const int o = (int)((base / HWc) % Cc);
    const float N = (float)(Bn * HWc);
    const float mean = s0[o] / N;
    const float var  = s1[o] / N - mean * mean;
    const float rstd = rsqrtf(var + BN_EPS);
    const float ga = gamma[o];
    const float be = beta[o];
    const float4 w4 = ((const float4*)wy)[i4];
    const float4 x4 = ((const float4*)x)[i4];
    float4 r;
    r.x = (w4.x - mean) * rstd * ga + be + x4.x;
    r.y = (w4.y - mean) * rstd * ga + be + x4.y;
    r.z = (w4.z - mean) * rstd * ga + be + x4.z;
    r.w = (w4.w - mean) * rstd * ga + be + x4.w;
    ((float4*)out)[i4] = r;
}

// ---------------------------------------------------------------------------
extern "C" void kernel_launch(void* const* d_in, const int* in_sizes, int n_in,
                              void* d_out, int out_size, void* d_ws, size_t ws_size,
                              hipStream_t stream) {
    const float* x     = (const float*)d_in[0];
    const float* g_w   = (const float*)d_in[1];
    const float* g_b   = (const float*)d_in[2];
    const float* th_w  = (const float*)d_in[3];
    const float* th_b  = (const float*)d_in[4];
    const float* ph_w  = (const float*)d_in[5];
    const float* ph_b  = (const float*)d_in[6];
    const float* w_w   = (const float*)d_in[7];
    const float* w_b   = (const float*)d_in[8];
    const float* gamma = (const float*)d_in[9];
    const float* beta  = (const float*)d_in[10];

    // Workspace aliasing (113.25 MB total, same bound as previous rounds):
    //  [0, 18.87M)      thph bf16 (B,HW,512)  -> later y bf16 (B,HW,IC) at [0,9.44M)
    //                   and post-S: wbf2 + stats at [9.44M, ...)
    //  [18.87M, 28.31M) g bf16 (B,IC,HW)
    //  [28.31M, 113.25M) Sreg: pre-S hosts xt bf16 (B,HW,C) + wcat + bias_thph;
    //                   S bf16 (B,HW,HW); post-PV wy fp32 (B,C,HW)
    char* base = (char*)d_ws;
    const size_t SZT = (size_t)Bn * HWc * ICc * 2;        // 9,437,184
    u16* thph = (u16*)base;                               // 18.87 MB
    u16* g    = (u16*)(base + 2 * SZT);                   // 9.44 MB
    char* Sreg = base + 3 * SZT;
    u16* S    = (u16*)Sreg;                               // 84.93 MB
    u16* xt   = (u16*)Sreg;                               // 18.87 MB (pre-S)
    u16* wcat = (u16*)(Sreg + (size_t)Bn * HWc * Cc * 2); // 786 KB (pre-S)
    float* bias_thph = (float*)(Sreg + (size_t)Bn * HWc * Cc * 2 + 786432);
    u16* y    = (u16*)base;                               // 9.44 MB (post-S)
    u16* wbf2 = (u16*)(base + SZT);                       // 262 KB (post-S)
    float* stats = (float*)(base + SZT + 262144);         // 4 KB (post-S)
    float* wy = (float*)Sreg;                             // 37.75 MB (post-PV)

    dim3 blk(256);
    const u16* thphw = wcat;                   // (512,512)
    const u16* gwb   = wcat + 262144;          // (256,512)

    cast_front<<<dim3(386), blk, 0, stream>>>(th_w, ph_w, g_w, th_b, ph_b,
                                              wcat, bias_thph);
    transpose_cast_x<<<dim3(HWc / 32, Cc / 64, Bn), blk, 0, stream>>>(x, xt);

    // thph[q][o] = sum_c xt[q][c]*thph_w[o][c] + bias  (M=2304,N=512,K=512)
    mfma_gemm<128, 0, false><<<dim3(4, 18, Bn), blk, 0, stream>>>(
        xt, thphw, thph, bias_thph, 1, Cc, Cc, Cc, 512,
        (size_t)HWc * Cc, 0, (size_t)HWc * 512, nullptr, nullptr);

    // g[ic][p] = sum_c g_w[ic][c]*xt[p][c] + g_b[ic]   (M=256,N=2304,K=512)
    mfma_gemm<64, 0, false><<<dim3(18, 4, Bn), blk, 0, stream>>>(
        gwb, xt, g, g_b, 2, Cc, Cc, Cc, HWc,
        0, (size_t)HWc * Cc, (size_t)ICc * HWc, nullptr, nullptr);

    // S = tht . pht^T   (M=N=2304, K=256); tht = thph cols 0..255, pht = +256
    mfma_gemm<128, 0, false><<<dim3(18, 18, Bn), blk, 0, stream>>>(
        thph, thph + 256, S, nullptr, 0, ICc, 512, 512, HWc,
        (size_t)HWc * 512, (size_t)HWc * 512, (size_t)HWc * HWc,
        nullptr, nullptr);

    // w_w -> bf16 and zero stats (into regions dead after S-gemm)
    cast_w<<<dim3(128), blk, 0, stream>>>(w_w, wbf2);
    hipMemsetAsync(stats, 0, 2 * Cc * sizeof(float), stream);

    // softmax rows, in place
    softmax_rows<<<dim3(Bn * HWc), dim3(192), 0, stream>>>(S);

    // y[q][ic] = sum_k P[q][k]*g[ic][k]  (M=2304,N=256,K=2304), TM=64: 576 blk
    mfma_gemm<64, 0, false><<<dim3(2, 36, Bn), blk, 0, stream>>>(
        S, g, y, nullptr, 0, HWc, HWc, HWc, ICc,
        (size_t)HWc * HWc, (size_t)ICc * HWc, (size_t)HWc * ICc,
        nullptr, nullptr);

    // wy[o][p] = sum_ic w_w[o][ic]*y[p][ic] + w_b[o]  (M=512,N=2304,K=256)
    // fp32 out + fused BN sum/sumsq
    mfma_gemm<128, 1, true><<<dim3(18, 4, Bn), blk, 0, stream>>>(
        wbf2, y, wy, w_b, 2, ICc, ICc, ICc, HWc,
        0, (size_t)HWc * ICc, (size_t)Cc * HWc, stats, stats + Cc);

    // BatchNorm apply (stats from raw sums) + affine + residual
    bn_apply<<<dim3((Bn * Cc * HWc) / 4 / 256), blk, 0, stream>>>(
        wy, x, stats, stats + Cc, gamma, beta, (float*)d_out);
}